// Round 6
// baseline (187.325 us; speedup 1.0000x reference)
//
#include <hip/hip_runtime.h>

// Problem constants
constexpr int B = 32, C = 32, T = 2048, D = 512;
constexpr float ALPHA = 0.1f;
constexpr float BETA  = 0.9f;
constexpr float LOG2_BETA = -0.15200309344504997f;  // log2(0.9)
constexpr float BETA8     = 0.43046721f;            // 0.9^8  (main-chunk carry)
constexpr float BETA14    = 0.22876792454961000f;   // 0.9^14 (halo-chunk carry)

// Native 4-float vector for __builtin_nontemporal_store.
typedef float floatx4 __attribute__((ext_vector_type(4)));

// Tiling: CHUNK=64 -> grid = 32x32 = 1024 blocks = 4 sequential blocks/CU
// with 3 resident (LDS 41.6 KB): co-resident blocks sit at DIFFERENT phases,
// so one block's store-bound GEMM overlaps others' staging/EWMA and the
// HBM write burst is spread over the whole kernel (r5 lesson: at grid==
// residency the blocks run A->B->C in lockstep and the store phase
// oversubscribes HBM ~10 TB/s instantaneous).
// 8 sub-threads/channel x SUB=8 main rows; halo one 14-chunk per side per
// sub-thread (HALO=112, beta^112 ~ 7.5e-6 truncation -- validated r5).
// Chunk sums composed via Horner: BETA14 across halo chunks, BETA8 across
// main chunks. PAD=293 (5 mod 32): phase-B column reads 2-way = free (m136).
constexpr int CHUNK = 64;
constexpr int SUB   = 8;                    // main rows per thread
constexpr int SUBH  = 14;                   // halo rows per thread
constexpr int NSUB  = CHUNK / SUB;          // 8
constexpr int HALO  = NSUB * SUBH;          // 112
constexpr int LEAD  = 116;                  // 112 halo + 1 diff + 3 align (mult of 4)
constexpr int WIN   = LEAD + CHUNK + HALO;  // 292
constexpr int PAD   = WIN + 1;              // 293

// ---------------------------------------------------------------------------
// Kernel 1: W_comb[e,c] = sum_d W_lin[e,d]*W_ve[d,c];
//           b_comb[e]   = sum_d W_lin[e,d]*b_ve[d] + b_lin[e]
// (out = smooth_C(diff) @ W_comb^T + b_comb -- EWMA commutes with Linear)
// ---------------------------------------------------------------------------
__global__ __launch_bounds__(256) void combine_weights(
    const float* __restrict__ W_ve, const float* __restrict__ b_ve,
    const float* __restrict__ W_lin, const float* __restrict__ b_lin,
    float* __restrict__ W_comb, float* __restrict__ b_comb) {
  int e  = blockIdx.x;
  int c  = threadIdx.x & 31;
  int ds = threadIdx.x >> 5;
  float acc = 0.f, accb = 0.f;
#pragma unroll 4
  for (int i = 0; i < 64; ++i) {
    int d = ds * 64 + i;
    float wl = W_lin[e * D + d];
    acc  += wl * W_ve[d * C + c];
    accb += wl * b_ve[d];
  }
  __shared__ float red[8][33];
  __shared__ float redb[8];
  red[ds][c] = acc;
  if (c == 0) redb[ds] = accb;
  __syncthreads();
  if (ds == 0) {
    float ssum = 0.f;
#pragma unroll
    for (int k = 0; k < 8; ++k) ssum += red[k][c];
    W_comb[e * C + c] = ssum;
    if (c == 0) {
      float sb = 0.f;
#pragma unroll
      for (int k = 0; k < 8; ++k) sb += redb[k];
      b_comb[e] = sb + b_lin[e];
    }
  }
}

// ---------------------------------------------------------------------------
// Kernel 2 (fused): diff + bidirectional EWMA in channel space + K=32 GEMM.
// grid = (T/CHUNK=32, B=32) = 1024 blocks, 256 threads.
// __launch_bounds__(256,3): cap VGPR so 3 blocks fit (LDS already allows 3).
// ---------------------------------------------------------------------------
__global__ __launch_bounds__(256, 3) void fused_main(
    const float* __restrict__ x, const float* __restrict__ W_comb,
    const float* __restrict__ b_comb, float* __restrict__ out) {
  int b   = blockIdx.y;
  int t0  = blockIdx.x * CHUNK;
  int wlo = t0 - LEAD;  // staged window covers global t in [wlo, wlo+WIN)

  __shared__ float xl[C * PAD];     // 37.5 KB; reused as s-tile in phase C
  __shared__ float Lf[2][NSUB][C];  // fwd chunk sums: [0]=halo [1]=main (2 KB)
  __shared__ float Lb[2][NSUB][C];  // bwd chunk sums (2 KB)
  const float* xb = x + (size_t)b * C * T;

  int c   = threadIdx.x & 31;
  int sub = threadIdx.x >> 5;

  // last-diff for the exact bwd init-term correction
  float dlast = xb[c * T + (T - 1)] - xb[c * T + (T - 2)];

  // ---- Phase A: staging ----
  if (wlo >= 0 && wlo + WIN <= T) {
    // interior (bx 2..29): 16B-aligned float4 global loads (wlo%4==0).
    for (int idx = threadIdx.x; idx < C * (WIN / 4); idx += 256) {
      int cc = idx / (WIN / 4);  // compile-time divisor (73)
      int q  = idx - cc * (WIN / 4);
      float4 v   = *(const float4*)(xb + cc * T + wlo + 4 * q);
      float* dst = xl + cc * PAD + 4 * q;
      dst[0] = v.x; dst[1] = v.y; dst[2] = v.z; dst[3] = v.w;
    }
  } else {
    // edge (bx 0,1,30,31): scalar clamped staging (DD==0 for t<=0, t>=T).
    for (int idx = threadIdx.x; idx < C * WIN; idx += 256) {
      int cc = idx / WIN;  // compile-time divisor (292)
      int tt = idx - cc * WIN;
      int t  = min(max(wlo + tt, 0), T - 1);
      xl[cc * PAD + tt] = xb[cc * T + t];
    }
  }
  __syncthreads();

  // ---- Phase B1: per-chunk local scans (zero-init): fwd+bwd, halo+main ----
  int ts = t0 + sub * SUB;
  const float* xc = xl + c * PAD - wlo;  // index directly by global t
#define DD(t) (xc[(t)] - xc[(t) - 1])

  int ha = t0 - HALO  + sub * SUBH;  // fwd-halo chunk (14 rows)
  int ba = t0 + CHUNK + sub * SUBH;  // bwd-halo chunk (14 rows)
  float fh = 0.f, bh = 0.f;
#pragma unroll
  for (int i = 0; i < SUBH; ++i) {
    fh = ALPHA * DD(ha + i)            + BETA * fh;  // ascending
    bh = ALPHA * DD(ba + SUBH - 1 - i) + BETA * bh;  // descending
  }
  float lr[SUB], rl[SUB];
  float fm = 0.f, bm = 0.f;
#pragma unroll
  for (int i = 0; i < SUB; ++i) {
    fm = ALPHA * DD(ts + i) + BETA * fm;
    lr[i] = fm;  // raw fwd scan (no carry yet)
    bm = ALPHA * DD(ts + SUB - 1 - i) + BETA * bm;
    rl[SUB - 1 - i] = bm;  // raw bwd scan
  }
  Lf[0][sub][c] = fh;
  Lf[1][sub][c] = lr[SUB - 1];
  Lb[0][sub][c] = bh;
  Lb[1][sub][c] = rl[0];
  __syncthreads();  // scratch visible; also: all xl reads done -> xl reusable
#undef DD

  // ---- Phase B2: Horner carry composition + in-register combine ----
  // S(t0-1) = sum_h beta^(14(7-h)) Lf_halo[h]  (BETA14 Horner);
  // main-chunk carry: C_s = beta^(8s) S + sum_{j<s} beta^(8(s-1-j)) Lf_main[j]
  // (BETA8 Horner, predicated trip). B_s mirrored from the right.
  float Cc = 0.f, Bc = 0.f;
#pragma unroll
  for (int h = 0; h < NSUB; ++h) {
    Cc = BETA14 * Cc + Lf[0][h][c];
    Bc = BETA14 * Bc + Lb[0][NSUB - 1 - h][c];
  }
#pragma unroll
  for (int j = 0; j < NSUB - 1; ++j) {  // predicated (sub-dependent trip)
    float cn = BETA8 * Cc + Lf[1][j][c];
    float bn = BETA8 * Bc + Lb[1][NSUB - 1 - j][c];
    Cc = (j < sub)            ? cn : Cc;
    Bc = (NSUB - 1 - j > sub) ? bn : Bc;
  }
  // lr_true[i] = lr_raw[i] + beta^(i+1) C_s ; rl_true[i] = rl_raw[i] + beta^(SUB-i) B_s
  // plus exact right-edge init term beta^(T-t) * d[T-1]  (since 1-ALPHA == BETA)
  float f = BETA * Cc;
#pragma unroll
  for (int i = 0; i < SUB; ++i) { lr[i] += f; f *= BETA; }
  float g = BETA * Bc;
  float e = exp2f((float)(T - ts - (SUB - 1)) * LOG2_BETA);  // beta^(T-te)
#pragma unroll
  for (int i = SUB - 1; i >= 0; --i) {
    lr[i] = 0.5f * (lr[i] + (rl[i] + g) + e * dlast);
    g *= BETA;
    e *= BETA;
  }

  // ---- s-tile into reused LDS ----
  float* sbuf = xl;  // s[tloc*C + c], tloc in [0, CHUNK)
  {
    int tbase = sub * SUB;
#pragma unroll
    for (int i = 0; i < SUB; ++i) sbuf[(tbase + i) * C + c] = lr[i];
  }

  // W rows + bias into registers, loaded HERE (after lr/rl pressure is dead;
  // global loads issue before the barrier, latency hides under the wait).
  int li   = threadIdx.x & 127;
  int half = threadIdx.x >> 7;
  int e0   = li * 4;
  float w[4][C], bias[4];
#pragma unroll
  for (int j = 0; j < 4; ++j) {
    const float4* wr = (const float4*)(W_comb + (e0 + j) * C);
#pragma unroll
    for (int c4 = 0; c4 < C / 4; ++c4) {
      float4 wv = wr[c4];
      w[j][c4 * 4 + 0] = wv.x;
      w[j][c4 * 4 + 1] = wv.y;
      w[j][c4 * 4 + 2] = wv.z;
      w[j][c4 * 4 + 3] = wv.w;
    }
    bias[j] = b_comb[e0 + j];
  }
  __syncthreads();

  // ---- Phase C: GEMM (broadcast ds_read_b128, nontemporal streamed out) ----
  const float* srow = sbuf + half * (CHUNK / 2) * C;
  float* orow = out + ((size_t)b * T + t0 + half * (CHUNK / 2)) * D + e0;

#pragma unroll 2
  for (int t = 0; t < CHUNK / 2; ++t) {
    float a[4], a2[4];
#pragma unroll
    for (int j = 0; j < 4; ++j) { a[j] = bias[j]; a2[j] = 0.f; }
    const float4* sr4 = (const float4*)(srow + t * C);
#pragma unroll
    for (int c4 = 0; c4 < C / 4; ++c4) {
      float4 sv = sr4[c4];  // broadcast ds_read_b128
      int cc = c4 * 4;
#pragma unroll
      for (int j = 0; j < 4; ++j) {
        a[j]  += sv.x * w[j][cc + 0];
        a2[j] += sv.y * w[j][cc + 1];
        a[j]  += sv.z * w[j][cc + 2];
        a2[j] += sv.w * w[j][cc + 3];
      }
    }
    floatx4 o;
    o.x = a[0] + a2[0];
    o.y = a[1] + a2[1];
    o.z = a[2] + a2[2];
    o.w = a[3] + a2[3];
    __builtin_nontemporal_store(o, (floatx4*)(orow + (size_t)t * D));
  }
}

// ---------------------------------------------------------------------------
extern "C" void kernel_launch(void* const* d_in, const int* in_sizes, int n_in,
                              void* d_out, int out_size, void* d_ws, size_t ws_size,
                              hipStream_t stream) {
  const float* x     = (const float*)d_in[0];  // [B,C,T]
  const float* W_ve  = (const float*)d_in[1];  // [D,C]
  const float* b_ve  = (const float*)d_in[2];  // [D]
  const float* W_lin = (const float*)d_in[3];  // [D,D]
  const float* b_lin = (const float*)d_in[4];  // [D]
  float* out = (float*)d_out;                  // [B,T,D]

  // workspace: W_comb [D*C], b_comb [D]
  float* W_comb = (float*)d_ws;
  float* b_comb = W_comb + (size_t)D * C;

  combine_weights<<<D, 256, 0, stream>>>(W_ve, b_ve, W_lin, b_lin, W_comb, b_comb);
  fused_main<<<dim3(T / CHUNK, B), 256, 0, stream>>>(x, W_comb, b_comb, out);
}

// Round 8
// 185.894 us; speedup vs baseline: 1.0077x; 1.0077x over previous
//
#include <hip/hip_runtime.h>

// Problem constants
constexpr int B = 32, C = 32, T = 2048, D = 512;
constexpr float ALPHA = 0.1f;
constexpr float BETA  = 0.9f;
constexpr float LOG2_BETA = -0.15200309344504997f;  // log2(0.9)
constexpr float BETA16    = 0.18530201888518410f;   // 0.9^16 (main-chunk carry)
constexpr float BETA14    = 0.22876792454961000f;   // 0.9^14 (halo-chunk carry)

using short8 = __attribute__((ext_vector_type(8))) short;  // 8 bf16 (MFMA A/B frag)
using f32x4  = __attribute__((ext_vector_type(4))) float;  // MFMA C/D frag

// Tiling (r5 structure -- r6's CHUNK=64 regressed: staging x1.64, halo x1.47):
// CHUNK=128, 8 sub-threads/channel x SUB=16 main rows; cooperative halo
// HALO=112 (one 14-chunk per side per sub-thread; beta^112 ~ 7.5e-6).
// Horner composition: BETA14 across halo chunks, BETA16 across main chunks.
// PAD=357 (5 mod 32): phase-B column reads 2-way bank-aliased = free (m136).
constexpr int CHUNK = 128;
constexpr int SUB   = 16;                   // main rows per thread
constexpr int SUBH  = 14;                   // halo rows per thread
constexpr int NSUB  = CHUNK / SUB;          // 8
constexpr int HALO  = NSUB * SUBH;          // 112
constexpr int LEAD  = 116;                  // 112 halo + 1 diff + 3 align (mult of 4)
constexpr int WIN   = LEAD + CHUNK + HALO;  // 356
constexpr int PAD   = WIN + 1;              // 357

// RNE float->bf16 (finite values; standard bit trick)
__device__ __forceinline__ unsigned short rne_bf16(float f) {
  unsigned int u = __float_as_uint(f);
  return (unsigned short)((u + 0x7fffu + ((u >> 16) & 1u)) >> 16);
}
// exact split: v = hi + lo + O(2^-18 |v|)   (v - float(hi) is exact, Sterbenz)
__device__ __forceinline__ void bf16_split(float v, unsigned short& hi,
                                           unsigned short& lo) {
  hi = rne_bf16(v);
  float fh = __uint_as_float(((unsigned int)hi) << 16);
  lo = rne_bf16(v - fh);
}

// ---------------------------------------------------------------------------
// Kernel 1: W_comb[e,c] = sum_d W_lin[e,d]*W_ve[d,c];
//           b_comb[e]   = sum_d W_lin[e,d]*b_ve[d] + b_lin[e]
// Emitted directly as split-bf16 (w_hi + w_lo) for the MFMA consumer.
// ---------------------------------------------------------------------------
__global__ __launch_bounds__(256) void combine_weights(
    const float* __restrict__ W_ve, const float* __restrict__ b_ve,
    const float* __restrict__ W_lin, const float* __restrict__ b_lin,
    unsigned short* __restrict__ w_hi, unsigned short* __restrict__ w_lo,
    float* __restrict__ b_comb) {
  int e  = blockIdx.x;
  int c  = threadIdx.x & 31;
  int ds = threadIdx.x >> 5;
  float acc = 0.f, accb = 0.f;
#pragma unroll 4
  for (int i = 0; i < 64; ++i) {
    int d = ds * 64 + i;
    float wl = W_lin[e * D + d];
    acc  += wl * W_ve[d * C + c];
    accb += wl * b_ve[d];
  }
  __shared__ float red[8][33];
  __shared__ float redb[8];
  red[ds][c] = acc;
  if (c == 0) redb[ds] = accb;
  __syncthreads();
  if (ds == 0) {
    float ssum = 0.f;
#pragma unroll
    for (int k = 0; k < 8; ++k) ssum += red[k][c];
    unsigned short h, l;
    bf16_split(ssum, h, l);
    w_hi[e * C + c] = h;
    w_lo[e * C + c] = l;
    if (c == 0) {
      float sb = 0.f;
#pragma unroll
      for (int k = 0; k < 8; ++k) sb += redb[k];
      b_comb[e] = sb + b_lin[e];
    }
  }
}

// ---------------------------------------------------------------------------
// Kernel 2 (fused): diff + bidirectional EWMA in channel space + MFMA GEMM.
// grid = (T/CHUNK=16, B=32) = 512 blocks, 256 threads (4 waves).
// Phase C: split-bf16 MFMA (16x16x32). out = s_hi*W_hi + s_lo*W_hi + s_hi*W_lo
// (dropped s_lo*W_lo term ~2^-18 relative). Per wave: 16 LDS b128 reads +
// 192 MFMA + 256 scalar stores -> phase C is purely HBM-store-bound.
// A/B k-maps are symmetric (same lane>>4 grouping), so the exact HW k-order
// cancels between operands; C/D layout col=lane&15,row=(lane>>4)*4+reg (m89).
// ---------------------------------------------------------------------------
__global__ __launch_bounds__(256, 2) void fused_main(
    const float* __restrict__ x, const unsigned short* __restrict__ w_hi,
    const unsigned short* __restrict__ w_lo, const float* __restrict__ b_comb,
    float* __restrict__ out) {
  int b   = blockIdx.y;
  int t0  = blockIdx.x * CHUNK;
  int wlo = t0 - LEAD;  // staged window covers global t in [wlo, wlo+WIN)

  __shared__ float xl[C * PAD];     // 44.6 KB; reused as bf16 s-tile in phase C
  __shared__ float Lf[2][NSUB][C];  // fwd chunk sums: [0]=halo [1]=main (2 KB)
  __shared__ float Lb[2][NSUB][C];  // bwd chunk sums (2 KB)
  const float* xb = x + (size_t)b * C * T;

  int c   = threadIdx.x & 31;
  int sub = threadIdx.x >> 5;

  // last-diff for the exact bwd init-term correction
  float dlast = xb[c * T + (T - 1)] - xb[c * T + (T - 2)];

  // ---- Phase A: staging ----
  if (wlo >= 0 && wlo + WIN <= T) {
    // interior (bx 1..14): 16B-aligned float4 global loads (wlo%4==0).
    for (int idx = threadIdx.x; idx < C * (WIN / 4); idx += 256) {
      int cc = idx / (WIN / 4);  // compile-time divisor (89)
      int q  = idx - cc * (WIN / 4);
      float4 v   = *(const float4*)(xb + cc * T + wlo + 4 * q);
      float* dst = xl + cc * PAD + 4 * q;
      dst[0] = v.x; dst[1] = v.y; dst[2] = v.z; dst[3] = v.w;
    }
  } else {
    // edge (bx 0, 15): scalar clamped staging (DD==0 for t<=0, t>=T).
    for (int idx = threadIdx.x; idx < C * WIN; idx += 256) {
      int cc = idx / WIN;  // compile-time divisor (356)
      int tt = idx - cc * WIN;
      int t  = min(max(wlo + tt, 0), T - 1);
      xl[cc * PAD + tt] = xb[cc * T + t];
    }
  }
  __syncthreads();

  // ---- Phase B1: per-chunk local scans (zero-init): fwd+bwd, halo+main ----
  int ts = t0 + sub * SUB;
  const float* xc = xl + c * PAD - wlo;  // index directly by global t
#define DD(t) (xc[(t)] - xc[(t) - 1])

  int ha = t0 - HALO  + sub * SUBH;  // fwd-halo chunk (14 rows)
  int ba = t0 + CHUNK + sub * SUBH;  // bwd-halo chunk (14 rows)
  float fh = 0.f, bh = 0.f;
#pragma unroll
  for (int i = 0; i < SUBH; ++i) {
    fh = ALPHA * DD(ha + i)            + BETA * fh;  // ascending
    bh = ALPHA * DD(ba + SUBH - 1 - i) + BETA * bh;  // descending
  }
  float lr[SUB], rl[SUB];
  float fm = 0.f, bm = 0.f;
#pragma unroll
  for (int i = 0; i < SUB; ++i) {
    fm = ALPHA * DD(ts + i) + BETA * fm;
    lr[i] = fm;  // raw fwd scan (no carry yet)
    bm = ALPHA * DD(ts + SUB - 1 - i) + BETA * bm;
    rl[SUB - 1 - i] = bm;  // raw bwd scan
  }
  Lf[0][sub][c] = fh;
  Lf[1][sub][c] = lr[SUB - 1];
  Lb[0][sub][c] = bh;
  Lb[1][sub][c] = rl[0];
  __syncthreads();  // scratch visible; also: all xl reads done -> xl reusable
#undef DD

  // ---- Phase B2: Horner carry composition + in-register combine ----
  float Cc = 0.f, Bc = 0.f;
#pragma unroll
  for (int h = 0; h < NSUB; ++h) {
    Cc = BETA14 * Cc + Lf[0][h][c];
    Bc = BETA14 * Bc + Lb[0][NSUB - 1 - h][c];
  }
#pragma unroll
  for (int j = 0; j < NSUB - 1; ++j) {  // predicated (sub-dependent trip)
    float cn = BETA16 * Cc + Lf[1][j][c];
    float bn = BETA16 * Bc + Lb[1][NSUB - 1 - j][c];
    Cc = (j < sub)            ? cn : Cc;
    Bc = (NSUB - 1 - j > sub) ? bn : Bc;
  }
  // lr_true[i] = lr_raw[i] + beta^(i+1) C_s ; rl_true[i] = rl_raw[i] + beta^(SUB-i) B_s
  // plus exact right-edge init term beta^(T-t) * d[T-1]  (since 1-ALPHA == BETA)
  float f = BETA * Cc;
#pragma unroll
  for (int i = 0; i < SUB; ++i) { lr[i] += f; f *= BETA; }
  float g = BETA * Bc;
  float e = exp2f((float)(T - ts - (SUB - 1)) * LOG2_BETA);  // beta^(T-te)
#pragma unroll
  for (int i = SUB - 1; i >= 0; --i) {
    lr[i] = 0.5f * (lr[i] + (rl[i] + g) + e * dlast);
    g *= BETA;
    e *= BETA;
  }

  // ---- s-tile into reused LDS as split-bf16 [CHUNK][C] hi | lo ----
  unsigned short* sh = (unsigned short*)xl;  // 8 KB
  unsigned short* sl = sh + CHUNK * C;       // 8 KB
  {
    int tbase = sub * SUB;
#pragma unroll
    for (int i = 0; i < SUB; ++i) {
      unsigned short h, l;
      bf16_split(lr[i], h, l);
      sh[(tbase + i) * C + c] = h;  // 32 lanes x 2B contiguous: conflict-free
      sl[(tbase + i) * C + c] = l;
    }
  }

  // ---- W fragments + bias into registers (latency hides under barrier) ----
  int lane = threadIdx.x & 63;
  int wid  = threadIdx.x >> 6;   // wave id 0..3 -> e-range [128*wid, 128*wid+128)
  int we0  = wid * 128;
  int g8   = (lane >> 4) * 8;    // k-group base (symmetric for A and B)
  int ecol = lane & 15;          // N-column within e-tile
  short8 bwh[8], bwl[8];
  float bias8[8];
#pragma unroll
  for (int et = 0; et < 8; ++et) {
    int erow = we0 + et * 16 + ecol;
    bwh[et] = *(const short8*)(w_hi + erow * C + g8);   // 16B coalesced
    bwl[et] = *(const short8*)(w_lo + erow * C + g8);
    bias8[et] = b_comb[erow];
  }
  __syncthreads();

  // ---- Phase C: MFMA GEMM, nontemporal streamed out ----
  int a_off = ecol * C + g8;  // A frag: row = lane&15 (t within tile), k = g8..g8+7
#pragma unroll 2
  for (int tt = 0; tt < CHUNK / 16; ++tt) {
    short8 a_hi = *(const short8*)(sh + tt * 16 * C + a_off);  // ds_read_b128
    short8 a_lo = *(const short8*)(sl + tt * 16 * C + a_off);
    float* ob = out + ((size_t)b * T + t0 + tt * 16 + (lane >> 4) * 4) * D
                + we0 + ecol;
#pragma unroll
    for (int et = 0; et < 8; ++et) {
      f32x4 acc = {bias8[et], bias8[et], bias8[et], bias8[et]};
      acc = __builtin_amdgcn_mfma_f32_16x16x32_bf16(a_hi, bwh[et], acc, 0, 0, 0);
      acc = __builtin_amdgcn_mfma_f32_16x16x32_bf16(a_lo, bwh[et], acc, 0, 0, 0);
      acc = __builtin_amdgcn_mfma_f32_16x16x32_bf16(a_hi, bwl[et], acc, 0, 0, 0);
      // C/D: col = lane&15 (e), row = (lane>>4)*4 + r (t) -- m89-verified
#pragma unroll
      for (int r = 0; r < 4; ++r)
        __builtin_nontemporal_store(acc[r], ob + (size_t)r * D + et * 16);
    }
  }
}

// ---------------------------------------------------------------------------
extern "C" void kernel_launch(void* const* d_in, const int* in_sizes, int n_in,
                              void* d_out, int out_size, void* d_ws, size_t ws_size,
                              hipStream_t stream) {
  const float* x     = (const float*)d_in[0];  // [B,C,T]
  const float* W_ve  = (const float*)d_in[1];  // [D,C]
  const float* b_ve  = (const float*)d_in[2];  // [D]
  const float* W_lin = (const float*)d_in[3];  // [D,D]
  const float* b_lin = (const float*)d_in[4];  // [D]
  float* out = (float*)d_out;                  // [B,T,D]

  // workspace: w_hi bf16 [D*C] | w_lo bf16 [D*C] | b_comb f32 [D]
  unsigned short* w_hi = (unsigned short*)d_ws;
  unsigned short* w_lo = w_hi + (size_t)D * C;
  float* b_comb        = (float*)(w_lo + (size_t)D * C);

  combine_weights<<<D, 256, 0, stream>>>(W_ve, b_ve, W_lin, b_lin, w_hi, w_lo, b_comb);
  fused_main<<<dim3(T / CHUNK, B), 256, 0, stream>>>(x, w_hi, w_lo, b_comb, out);
}